// Round 4
// baseline (4346.225 us; speedup 1.0000x reference)
//
#include <hip/hip_runtime.h>
#include <hip/hip_cooperative_groups.h>
#include <math.h>

namespace cg = cooperative_groups;

// Real grid (match reference): 421 x 421 E-grid, source at (210,210)
#define NXr 421
#define CXr 210
#define NSTEPS_C 200

// Temporal blocking: block = 16x16 threads, each thread owns a 2x2 cell quad.
// EXT=32 halo-extended tile, Kt=8 fused steps, owned interior Bt=16.
#define Bt   16
#define Kt   8
#define EXT  32
#define SPITCH 34                  // even => float2-aligned LDS rows
#define NBLK 27                    // 27*16 = 432 computational domain
#define NPHASE (NSTEPS_C / Kt)     // 25

// Padded zero-ring layout: fields are PP x PP with the computational domain
// [0,432)^2 at offset (PAD,PAD). Coefficient tables are zero outside the real
// 421^2 domain, so every cell outside it provably stays 0 forever -> all hot
// loads/stores are unconditional float2.
#define PP   448
#define PAD  8
#define FSZ  (PP * PP)             // floats per padded field

struct PParams {
    float *aEz, *aEo, *aJz, *aJo, *aHx, *aHy;   // state set A
    float *bEz, *bEo, *bJz, *bJo, *bHx, *bHy;   // state set B
    const float *dexP, *deyP, *aexP, *aeyP, *ahxP, *ahyP;  // padded 1-D tables
    const float *C1a, *C2a, *Cbdxa, *Cbdya;
    const float *Caa, *Cba, *Cca, *Cda, *Cea, *dbhxa, *dbhya;
    const float *src;
};

// ---------------------------------------------------------------------------
// Init: zero both padded state sets; build the six padded coefficient tables.
// Table index k -> real coord g = k - PAD.
//   dexP/deyP additionally fold the interior mask (nonzero only for 1..419).
// ---------------------------------------------------------------------------
__global__ void init_kernel(const float* __restrict__ sig_ex,
                            const float* __restrict__ sig_ey,
                            const float* __restrict__ sig_hx,
                            const float* __restrict__ sig_hy,
                            float de_fac, float dh_fac,
                            float* __restrict__ zero_base, int n_zero,
                            float* __restrict__ dexP, float* __restrict__ deyP,
                            float* __restrict__ aexP, float* __restrict__ aeyP,
                            float* __restrict__ ahxP, float* __restrict__ ahyP)
{
    int t = blockIdx.x * blockDim.x + threadIdx.x;
    int stride = gridDim.x * blockDim.x;
    for (int k = t; k < n_zero; k += stride) zero_base[k] = 0.0f;
    if (t < PP) {
        int g = t - PAD;
        dexP[t] = (g >= 1 && g <= NXr - 2) ? expf(-sig_ex[g] * de_fac) : 0.0f;
        deyP[t] = (g >= 1 && g <= NXr - 2) ? expf(-sig_ey[g] * de_fac) : 0.0f;
        aexP[t] = (g >= 0 && g <  NXr)     ? expf(-sig_ex[g] * dh_fac) : 0.0f;
        aeyP[t] = (g >= 0 && g <  NXr)     ? expf(-sig_ey[g] * dh_fac) : 0.0f;
        ahxP[t] = (g >= 0 && g <  NXr - 1) ? expf(-sig_hx[g] * dh_fac) : 0.0f;
        ahyP[t] = (g >= 0 && g <  NXr - 1) ? expf(-sig_hy[g] * dh_fac) : 0.0f;
    }
}

// ---------------------------------------------------------------------------
// One temporal-blocked phase (Kt=8 steps) for one block's tile.
// Identical arithmetic to the round-3 verified kernel; only the I/O is now
// unconditional padded float2. Register state: 2x2 cells x 6 fields.
// ---------------------------------------------------------------------------
__device__ __forceinline__ void do_phase(
    const float* cEz, const float* cEo, const float* cJz,
    const float* cJo, const float* cHx, const float* cHy,
    float* nEz, float* nEo, float* nJz, float* nJo, float* nHx, float* nHy,
    const float* src, int n0,
    int ti, int tj, int r0, int c0,
    const float (&dHx)[2][2], const float (&dHy)[2][2], const float (&dE)[2][2],
    const bool (&isSrc)[2][2],
    float (*sEz)[SPITCH], float (*sHx)[SPITCH], float (*sHy)[SPITCH],
    float ca, float cb, float cc, float cd, float ce, float ca1,
    float C1, float C2, float cbdx, float cbdy, float dbhx0, float dbhy0)
{
    const int li0 = 2 * ti, lj0 = 2 * tj;
    float ez[2][2], eo[2][2], jz[2][2], jo[2][2], hx[2][2], hy[2][2];
#pragma unroll
    for (int a = 0; a < 2; ++a) {
        int g = (r0 + a) * PP + c0;
        float2 v;
        v = *(const float2*)&cEz[g]; ez[a][0] = v.x; ez[a][1] = v.y;
        v = *(const float2*)&cEo[g]; eo[a][0] = v.x; eo[a][1] = v.y;
        v = *(const float2*)&cJz[g]; jz[a][0] = v.x; jz[a][1] = v.y;
        v = *(const float2*)&cJo[g]; jo[a][0] = v.x; jo[a][1] = v.y;
        v = *(const float2*)&cHx[g]; hx[a][0] = v.x; hx[a][1] = v.y;
        v = *(const float2*)&cHy[g]; hy[a][0] = v.x; hy[a][1] = v.y;
    }
    const bool edgeR = (tj == 15), edgeD = (ti == 15);
    const bool edgeU = (ti == 0),  edgeL = (tj == 0);

    for (int s = 0; s < Kt; ++s) {
        // publish Ez edges
        *(float2*)&sEz[li0][lj0] = make_float2(ez[0][0], ez[0][1]);
        sEz[li0 + 1][lj0] = ez[1][0];
        __syncthreads();

        float eR0 = edgeR ? 0.0f : sEz[li0][lj0 + 2];
        float eR1 = edgeR ? 0.0f : sEz[li0 + 1][lj0 + 2];
        float2 eD = edgeD ? make_float2(0.0f, 0.0f)
                          : *(float2*)&sEz[li0 + 2][lj0];

        hx[0][0] = dHx[0][0] * (hx[0][0] - dbhx0 * (ez[0][1] - ez[0][0]));
        hx[0][1] = dHx[0][1] * (hx[0][1] - dbhx0 * (eR0     - ez[0][1]));
        hx[1][0] = dHx[1][0] * (hx[1][0] - dbhx0 * (ez[1][1] - ez[1][0]));
        hx[1][1] = dHx[1][1] * (hx[1][1] - dbhx0 * (eR1     - ez[1][1]));

        hy[0][0] = dHy[0][0] * (hy[0][0] + dbhy0 * (ez[1][0] - ez[0][0]));
        hy[0][1] = dHy[0][1] * (hy[0][1] + dbhy0 * (ez[1][1] - ez[0][1]));
        hy[1][0] = dHy[1][0] * (hy[1][0] + dbhy0 * (eD.x     - ez[1][0]));
        hy[1][1] = dHy[1][1] * (hy[1][1] + dbhy0 * (eD.y     - ez[1][1]));

        // publish H edges (odd Hx column, odd Hy row)
        sHx[li0][lj0 + 1]     = hx[0][1];
        sHx[li0 + 1][lj0 + 1] = hx[1][1];
        *(float2*)&sHy[li0 + 1][lj0] = make_float2(hy[1][0], hy[1][1]);
        __syncthreads();

        float sv = src[n0 + s];
        float2 hyUp = edgeU ? make_float2(0.0f, 0.0f)
                            : *(float2*)&sHy[li0 - 1][lj0];
        float hxL0 = edgeL ? 0.0f : sHx[li0][lj0 - 1];
        float hxL1 = edgeL ? 0.0f : sHx[li0 + 1][lj0 - 1];

        float cHyv[2][2], cHxv[2][2];
        cHyv[0][0] = hy[0][0] - hyUp.x;   cHxv[0][0] = hx[0][0] - hxL0;
        cHyv[0][1] = hy[0][1] - hyUp.y;   cHxv[0][1] = hx[0][1] - hx[0][0];
        cHyv[1][0] = hy[1][0] - hy[0][0]; cHxv[1][0] = hx[1][0] - hxL1;
        cHyv[1][1] = hy[1][1] - hy[0][1]; cHxv[1][1] = hx[1][1] - hx[1][0];

#pragma unroll
        for (int a = 0; a < 2; ++a)
#pragma unroll
            for (int b = 0; b < 2; ++b) {
                float e = ez[a][b], eold = eo[a][b];
                float j = jz[a][b], jold = jo[a][b];
                float phi = ca1 * j + cb * jold + cd * e + ce * eold;
                float en = dE[a][b] *
                    (C1 * e + cbdx * cHyv[a][b] - cbdy * cHxv[a][b] - C2 * phi);
                if (isSrc[a][b]) en += sv;      // source after mask*de
                float jn = ca * j + cb * jold + cc * en + cd * e + ce * eold;
                eo[a][b] = e;  ez[a][b] = en;
                jo[a][b] = j;  jz[a][b] = jn;
            }
        // No 3rd barrier: next publish touches only sEz, whose step-s reads all
        // precede barrier 2; sHx/sHy step-s reads precede each thread's own
        // barrier-1 arrival of step s+1 (verified structure from round 3).
    }

    // store owned interior [Kt, Kt+Bt)^2 -> padded rows [bx*16+8, bx*16+24)
    if (ti >= 4 && ti < 12 && tj >= 4 && tj < 12) {
#pragma unroll
        for (int a = 0; a < 2; ++a) {
            int g = (r0 + a) * PP + c0;
            *(float2*)&nEz[g] = make_float2(ez[a][0], ez[a][1]);
            *(float2*)&nEo[g] = make_float2(eo[a][0], eo[a][1]);
            *(float2*)&nJz[g] = make_float2(jz[a][0], jz[a][1]);
            *(float2*)&nJo[g] = make_float2(jo[a][0], jo[a][1]);
            *(float2*)&nHx[g] = make_float2(hx[a][0], hx[a][1]);
            *(float2*)&nHy[g] = make_float2(hy[a][0], hy[a][1]);
        }
    }
}

// ---------------------------------------------------------------------------
// Persistent cooperative kernel: all 25 phases in one dispatch.
// ---------------------------------------------------------------------------
__global__ __launch_bounds__(256)
void persist_kernel(PParams p)
{
    cg::grid_group grid = cg::this_grid();

    const int tid = threadIdx.x;
    const int tj = tid & 15, ti = tid >> 4;
    const int r0 = (int)blockIdx.x * Bt + 2 * ti;   // padded row of cell (0,*)
    const int c0 = (int)blockIdx.y * Bt + 2 * tj;   // padded col of cell (*,0)

    const float ca = p.Caa[0], cb = p.Cba[0], cc = p.Cca[0];
    const float cd = p.Cda[0], ce = p.Cea[0];
    const float ca1 = ca + 1.0f;
    const float C1 = p.C1a[0], C2 = p.C2a[0];
    const float cbdx = p.Cbdxa[0], cbdy = p.Cbdya[0];
    const float dbhx0 = p.dbhxa[0], dbhy0 = p.dbhya[0];

    float dHx[2][2], dHy[2][2], dE[2][2];
    bool isSrc[2][2];
#pragma unroll
    for (int a = 0; a < 2; ++a)
#pragma unroll
        for (int b = 0; b < 2; ++b) {
            dHx[a][b] = p.aexP[r0 + a] * p.ahyP[c0 + b];
            dHy[a][b] = p.ahxP[r0 + a] * p.aeyP[c0 + b];
            dE[a][b]  = p.dexP[r0 + a] * p.deyP[c0 + b];
            isSrc[a][b] = (r0 + a == CXr + PAD) && (c0 + b == CXr + PAD);
        }

    __shared__ __align__(16) float sEz[EXT][SPITCH];
    __shared__ __align__(16) float sHx[EXT][SPITCH];
    __shared__ __align__(16) float sHy[EXT][SPITCH];

    for (int t = 0; t < NPHASE; ++t) {
        const bool odd = (t & 1) != 0;
        const float* cEz = odd ? p.bEz : p.aEz;
        const float* cEo = odd ? p.bEo : p.aEo;
        const float* cJz = odd ? p.bJz : p.aJz;
        const float* cJo = odd ? p.bJo : p.aJo;
        const float* cHx = odd ? p.bHx : p.aHx;
        const float* cHy = odd ? p.bHy : p.aHy;
        float* nEz = odd ? p.aEz : p.bEz;
        float* nEo = odd ? p.aEo : p.bEo;
        float* nJz = odd ? p.aJz : p.bJz;
        float* nJo = odd ? p.aJo : p.bJo;
        float* nHx = odd ? p.aHx : p.bHx;
        float* nHy = odd ? p.aHy : p.bHy;

        do_phase(cEz, cEo, cJz, cJo, cHx, cHy,
                 nEz, nEo, nJz, nJo, nHx, nHy,
                 p.src, t * Kt, ti, tj, r0, c0,
                 dHx, dHy, dE, isSrc, sEz, sHx, sHy,
                 ca, cb, cc, cd, ce, ca1, C1, C2, cbdx, cbdy, dbhx0, dbhy0);

        __threadfence();   // device-scope visibility before grid-wide release
        grid.sync();
    }
}

// ---------------------------------------------------------------------------
// Fallback: one phase per launch (no cooperative support needed).
// ---------------------------------------------------------------------------
__global__ __launch_bounds__(256)
void phase_kernel(PParams p, int t)
{
    const int tid = threadIdx.x;
    const int tj = tid & 15, ti = tid >> 4;
    const int r0 = (int)blockIdx.x * Bt + 2 * ti;
    const int c0 = (int)blockIdx.y * Bt + 2 * tj;

    const float ca = p.Caa[0], cb = p.Cba[0], cc = p.Cca[0];
    const float cd = p.Cda[0], ce = p.Cea[0];
    const float ca1 = ca + 1.0f;
    const float C1 = p.C1a[0], C2 = p.C2a[0];
    const float cbdx = p.Cbdxa[0], cbdy = p.Cbdya[0];
    const float dbhx0 = p.dbhxa[0], dbhy0 = p.dbhya[0];

    float dHx[2][2], dHy[2][2], dE[2][2];
    bool isSrc[2][2];
#pragma unroll
    for (int a = 0; a < 2; ++a)
#pragma unroll
        for (int b = 0; b < 2; ++b) {
            dHx[a][b] = p.aexP[r0 + a] * p.ahyP[c0 + b];
            dHy[a][b] = p.ahxP[r0 + a] * p.aeyP[c0 + b];
            dE[a][b]  = p.dexP[r0 + a] * p.deyP[c0 + b];
            isSrc[a][b] = (r0 + a == CXr + PAD) && (c0 + b == CXr + PAD);
        }

    __shared__ __align__(16) float sEz[EXT][SPITCH];
    __shared__ __align__(16) float sHx[EXT][SPITCH];
    __shared__ __align__(16) float sHy[EXT][SPITCH];

    const bool odd = (t & 1) != 0;
    const float* cEz = odd ? p.bEz : p.aEz;
    const float* cEo = odd ? p.bEo : p.aEo;
    const float* cJz = odd ? p.bJz : p.aJz;
    const float* cJo = odd ? p.bJo : p.aJo;
    const float* cHx = odd ? p.bHx : p.aHx;
    const float* cHy = odd ? p.bHy : p.aHy;
    float* nEz = odd ? p.aEz : p.bEz;
    float* nEo = odd ? p.aEo : p.bEo;
    float* nJz = odd ? p.aJz : p.bJz;
    float* nJo = odd ? p.aJo : p.bJo;
    float* nHx = odd ? p.aHx : p.bHx;
    float* nHy = odd ? p.aHy : p.bHy;

    do_phase(cEz, cEo, cJz, cJo, cHx, cHy,
             nEz, nEo, nJz, nJo, nHx, nHy,
             p.src, t * Kt, ti, tj, r0, c0,
             dHx, dHy, dE, isSrc, sEz, sHx, sHy,
             ca, cb, cc, cd, ce, ca1, C1, C2, cbdx, cbdy, dbhx0, dbhy0);
}

// ---------------------------------------------------------------------------
// Copy padded Ez -> dense 421x421 output.
// ---------------------------------------------------------------------------
__global__ void copy_out_kernel(const float* __restrict__ ezP,
                                float* __restrict__ out)
{
    int idx = blockIdx.x * blockDim.x + threadIdx.x;
    if (idx >= NXr * NXr) return;
    int gi = idx / NXr, gj = idx - gi * NXr;
    out[idx] = ezP[(gi + PAD) * PP + (gj + PAD)];
}

// ---------------------------------------------------------------------------
extern "C" void kernel_launch(void* const* d_in, const int* in_sizes, int n_in,
                              void* d_out, int out_size, void* d_ws, size_t ws_size,
                              hipStream_t stream)
{
    const float* src    = (const float*)d_in[0];
    const float* C1     = (const float*)d_in[1];
    const float* C2     = (const float*)d_in[2];
    const float* Cb_dx  = (const float*)d_in[3];
    const float* Cb_dy  = (const float*)d_in[4];
    const float* dbhx   = (const float*)d_in[5];
    const float* dbhy   = (const float*)d_in[6];
    const float* Ca     = (const float*)d_in[7];
    const float* Cb     = (const float*)d_in[8];
    const float* Cc     = (const float*)d_in[9];
    const float* Cd     = (const float*)d_in[10];
    const float* Ce     = (const float*)d_in[11];
    const float* sig_ex = (const float*)d_in[12];
    const float* sig_ey = (const float*)d_in[13];
    const float* sig_hx = (const float*)d_in[14];
    const float* sig_hy = (const float*)d_in[15];
    // d_in[16] = n_steps (always 200) — hard-coded for graph capture.

    const double EPS0 = 1e-9 / 36.0 / M_PI;
    const double MU0  = 4.0 * M_PI * 1e-7;
    const double C0   = 1.0 / sqrt(MU0 * EPS0);
    const double DXd  = 2.5e-8, DYd = 2.5e-8;
    const double DT   = 0.99 / C0 / sqrt(1.0 / (DXd * DXd) + 1.0 / (DYd * DYd));
    const float de_fac = (float)(DT / EPS0);
    const float dh_fac = (float)(DT / MU0);

    // Workspace layout: 12 padded fields (2 sets x 6) + 6 padded tables.
    float* w = (float*)d_ws;
    float* fields = w;                  // 12 * FSZ floats, zeroed by init
    w += 12 * (size_t)FSZ;
    float* dexP = w; w += PP;
    float* deyP = w; w += PP;
    float* aexP = w; w += PP;
    float* aeyP = w; w += PP;
    float* ahxP = w; w += PP;
    float* ahyP = w; w += PP;

    PParams p;
    p.aEz = fields + 0 * (size_t)FSZ;  p.aEo = fields + 1 * (size_t)FSZ;
    p.aJz = fields + 2 * (size_t)FSZ;  p.aJo = fields + 3 * (size_t)FSZ;
    p.aHx = fields + 4 * (size_t)FSZ;  p.aHy = fields + 5 * (size_t)FSZ;
    p.bEz = fields + 6 * (size_t)FSZ;  p.bEo = fields + 7 * (size_t)FSZ;
    p.bJz = fields + 8 * (size_t)FSZ;  p.bJo = fields + 9 * (size_t)FSZ;
    p.bHx = fields + 10 * (size_t)FSZ; p.bHy = fields + 11 * (size_t)FSZ;
    p.dexP = dexP; p.deyP = deyP; p.aexP = aexP; p.aeyP = aeyP;
    p.ahxP = ahxP; p.ahyP = ahyP;
    p.C1a = C1; p.C2a = C2; p.Cbdxa = Cb_dx; p.Cbdya = Cb_dy;
    p.Caa = Ca; p.Cba = Cb; p.Cca = Cc; p.Cda = Cd; p.Cea = Ce;
    p.dbhxa = dbhx; p.dbhya = dbhy;
    p.src = src;

    init_kernel<<<512, 256, 0, stream>>>(sig_ex, sig_ey, sig_hx, sig_hy,
                                         de_fac, dh_fac,
                                         fields, 12 * FSZ,
                                         dexP, deyP, aexP, aeyP, ahxP, ahyP);

    // Cooperative-launch capability + co-residency check (host-only queries;
    // graph-capture safe; same result every call).
    int dev = 0;
    hipGetDevice(&dev);
    hipDeviceProp_t prop;
    hipGetDeviceProperties(&prop, dev);
    int maxBlk = 0;
    hipOccupancyMaxActiveBlocksPerMultiprocessor(&maxBlk, persist_kernel, 256, 0);
    bool coop_ok = prop.cooperativeLaunch &&
                   (long long)maxBlk * prop.multiProcessorCount >= NBLK * NBLK;

    dim3 grd(NBLK, NBLK), blk(256);
    if (coop_ok) {
        void* kargs[] = { (void*)&p };
        hipLaunchCooperativeKernel((const void*)persist_kernel, grd, blk,
                                   kargs, 0, stream);
    } else {
        for (int t = 0; t < NPHASE; ++t)
            phase_kernel<<<grd, blk, 0, stream>>>(p, t);
    }

    // 25 phases starting from set A -> final state in set B.
    copy_out_kernel<<<(NXr * NXr + 255) / 256, 256, 0, stream>>>(p.bEz,
                                                                 (float*)d_out);
}

// Round 5
// 369.795 us; speedup vs baseline: 11.7531x; 11.7531x over previous
//
#include <hip/hip_runtime.h>
#include <math.h>

// Real grid (match reference): 421 x 421 E-grid, source at (210,210)
#define NXr 421
#define CXr 210
#define NSTEPS_C 200

// Temporal blocking: block = 16x16 threads, each thread owns a 2x2 cell quad.
// EXT=32 halo-extended tile, Kt=8 fused steps, owned interior Bt=16.
// 27x27 = 729 blocks (~2.85/CU). 25 launches; kernel-launch boundaries are the
// device-wide barrier (grid.sync() forced 447 MB/dispatch of cross-XCD
// coherence traffic in round 4 -- never again).
#define Bt   16
#define Kt   8
#define EXT  32
#define SPITCH 34                  // even => float2-aligned LDS rows
#define NBLK 27                    // 27*16 = 432 computational domain
#define NPHASE (NSTEPS_C / Kt)     // 25

// Padded zero-ring layout: fields are PP x PP with the computational domain
// [0,432)^2 at offset (PAD,PAD). Coefficient tables are zero outside the real
// 421^2 domain, so cells outside it provably stay 0 forever -> all hot
// loads/stores are unconditional float2. A zeroed guard row (PP floats) sits
// in front of the field block so ghost loads at padded row/col -1 are safe.
#define PP   448
#define PAD  8
#define FSZ  (PP * PP)             // floats per padded field

struct PParams {
    float *aEz, *aEo, *aJz, *aJo, *aHx, *aHy;   // state set A
    float *bEz, *bEo, *bJz, *bJo, *bHx, *bHy;   // state set B
    const float *dexP, *deyP, *aexP, *aeyP, *ahxP, *ahyP;  // padded 1-D tables
    const float *C1a, *C2a, *Cbdxa, *Cbdya;
    const float *Caa, *Cba, *Cca, *Cda, *Cea, *dbhxa, *dbhya;
    const float *src;
};

// ---------------------------------------------------------------------------
// Init: zero guard row + both padded state sets; build padded coeff tables.
// dexP/deyP fold the interior mask (nonzero only for real coords 1..419).
// ---------------------------------------------------------------------------
__global__ void init_kernel(const float* __restrict__ sig_ex,
                            const float* __restrict__ sig_ey,
                            const float* __restrict__ sig_hx,
                            const float* __restrict__ sig_hy,
                            float de_fac, float dh_fac,
                            float* __restrict__ zero_base, int n_zero,
                            float* __restrict__ dexP, float* __restrict__ deyP,
                            float* __restrict__ aexP, float* __restrict__ aeyP,
                            float* __restrict__ ahxP, float* __restrict__ ahyP)
{
    int t = blockIdx.x * blockDim.x + threadIdx.x;
    int stride = gridDim.x * blockDim.x;
    for (int k = t; k < n_zero; k += stride) zero_base[k] = 0.0f;
    if (t < PP) {
        int g = t - PAD;
        dexP[t] = (g >= 1 && g <= NXr - 2) ? expf(-sig_ex[g] * de_fac) : 0.0f;
        deyP[t] = (g >= 1 && g <= NXr - 2) ? expf(-sig_ey[g] * de_fac) : 0.0f;
        aexP[t] = (g >= 0 && g <  NXr)     ? expf(-sig_ex[g] * dh_fac) : 0.0f;
        aeyP[t] = (g >= 0 && g <  NXr)     ? expf(-sig_ey[g] * dh_fac) : 0.0f;
        ahxP[t] = (g >= 0 && g <  NXr - 1) ? expf(-sig_hx[g] * dh_fac) : 0.0f;
        ahyP[t] = (g >= 0 && g <  NXr - 1) ? expf(-sig_hy[g] * dh_fac) : 0.0f;
    }
}

// ---------------------------------------------------------------------------
// One temporal-blocked phase (Kt=8 steps), ONE barrier per step.
// Ez is the only field exchanged through LDS (parity-double-buffered tile:
// step s+1 stores to the other buffer, so the single barrier is WAR-safe).
// The H values a thread needs from its up/left neighbors are maintained as
// ghost registers (hyU[2], hxL[2]) updated redundantly from the exchanged Ez
// -- identical arithmetic to the neighbor's own update.
// Ghost contamination only reaches dE==0 cells or the discarded halo.
// ---------------------------------------------------------------------------
__global__ __launch_bounds__(256)
void phase_kernel(PParams p, int t)
{
    __shared__ __align__(16) float sEz[2][EXT][SPITCH];

    const int tid = threadIdx.x;
    const int tj = tid & 15, ti = tid >> 4;
    const int li0 = 2 * ti, lj0 = 2 * tj;
    const int r0 = (int)blockIdx.x * Bt + li0;   // padded row of cell (0,*)
    const int c0 = (int)blockIdx.y * Bt + lj0;   // padded col of cell (*,0)

    const float ca = p.Caa[0], cb = p.Cba[0], cc = p.Cca[0];
    const float cd = p.Cda[0], ce = p.Cea[0];
    const float ca1 = ca + 1.0f;
    const float C1 = p.C1a[0], C2 = p.C2a[0];
    const float cbdx = p.Cbdxa[0], cbdy = p.Cbdya[0];
    const float dbhx0 = p.dbhxa[0], dbhy0 = p.dbhya[0];

    // Per-cell damping products (interior mask folded into dE) + ghost damping
    float dHx[2][2], dHy[2][2], dE[2][2], dHyU[2], dHxL[2];
    bool isSrc[2][2];
#pragma unroll
    for (int a = 0; a < 2; ++a)
#pragma unroll
        for (int b = 0; b < 2; ++b) {
            dHx[a][b] = p.aexP[r0 + a] * p.ahyP[c0 + b];
            dHy[a][b] = p.ahxP[r0 + a] * p.aeyP[c0 + b];
            dE[a][b]  = p.dexP[r0 + a] * p.deyP[c0 + b];
            isSrc[a][b] = (r0 + a == CXr + PAD) && (c0 + b == CXr + PAD);
        }
    {
        float ahxU = (r0 > 0) ? p.ahxP[r0 - 1] : 0.0f;   // table idx guard
        float ahyL = (c0 > 0) ? p.ahyP[c0 - 1] : 0.0f;
        dHyU[0] = ahxU * p.aeyP[c0];
        dHyU[1] = ahxU * p.aeyP[c0 + 1];
        dHxL[0] = p.aexP[r0] * ahyL;
        dHxL[1] = p.aexP[r0 + 1] * ahyL;
    }

    const bool odd = (t & 1) != 0;
    const float* cEz = odd ? p.bEz : p.aEz;
    const float* cEo = odd ? p.bEo : p.aEo;
    const float* cJz = odd ? p.bJz : p.aJz;
    const float* cJo = odd ? p.bJo : p.aJo;
    const float* cHx = odd ? p.bHx : p.aHx;
    const float* cHy = odd ? p.bHy : p.aHy;
    float* nEz = odd ? p.aEz : p.bEz;
    float* nEo = odd ? p.aEo : p.bEo;
    float* nJz = odd ? p.aJz : p.bJz;
    float* nJo = odd ? p.aJo : p.bJo;
    float* nHx = odd ? p.aHx : p.bHx;
    float* nHy = odd ? p.aHy : p.bHy;

    // Load 2x2 register state (unconditional padded float2)
    float ez[2][2], eo[2][2], jz[2][2], jo[2][2], hx[2][2], hy[2][2];
#pragma unroll
    for (int a = 0; a < 2; ++a) {
        int g = (r0 + a) * PP + c0;
        float2 v;
        v = *(const float2*)&cEz[g]; ez[a][0] = v.x; ez[a][1] = v.y;
        v = *(const float2*)&cEo[g]; eo[a][0] = v.x; eo[a][1] = v.y;
        v = *(const float2*)&cJz[g]; jz[a][0] = v.x; jz[a][1] = v.y;
        v = *(const float2*)&cJo[g]; jo[a][0] = v.x; jo[a][1] = v.y;
        v = *(const float2*)&cHx[g]; hx[a][0] = v.x; hx[a][1] = v.y;
        v = *(const float2*)&cHy[g]; hy[a][0] = v.x; hy[a][1] = v.y;
    }
    // Ghost H (row above / col left of the quad); guard row makes idx -1 safe
    float hyU[2], hxL[2];
    {
        float2 v = *(const float2*)&cHy[(r0 - 1) * PP + c0];
        hyU[0] = v.x; hyU[1] = v.y;
        hxL[0] = cHx[r0 * PP + c0 - 1];
        hxL[1] = cHx[(r0 + 1) * PP + c0 - 1];
    }

    const bool edgeR = (tj == 15), edgeD = (ti == 15);
    const bool edgeU = (ti == 0),  edgeL = (tj == 0);
    const int n0 = t * Kt;

    for (int s = 0; s < Kt; ++s) {
        float (*S)[SPITCH] = sEz[s & 1];
        // publish all 4 Ez cells
        *(float2*)&S[li0][lj0]     = make_float2(ez[0][0], ez[0][1]);
        *(float2*)&S[li0 + 1][lj0] = make_float2(ez[1][0], ez[1][1]);
        __syncthreads();

        float eR0 = edgeR ? 0.0f : S[li0][lj0 + 2];
        float eR1 = edgeR ? 0.0f : S[li0 + 1][lj0 + 2];
        float2 eD  = edgeD ? make_float2(0.0f, 0.0f)
                           : *(float2*)&S[li0 + 2][lj0];
        float2 eU  = edgeU ? make_float2(0.0f, 0.0f)
                           : *(float2*)&S[li0 - 1][lj0];
        float eL0 = edgeL ? 0.0f : S[li0][lj0 - 1];
        float eL1 = edgeL ? 0.0f : S[li0 + 1][lj0 - 1];

        // ---- H update (own 2x2) ----
        hx[0][0] = dHx[0][0] * (hx[0][0] - dbhx0 * (ez[0][1] - ez[0][0]));
        hx[0][1] = dHx[0][1] * (hx[0][1] - dbhx0 * (eR0     - ez[0][1]));
        hx[1][0] = dHx[1][0] * (hx[1][0] - dbhx0 * (ez[1][1] - ez[1][0]));
        hx[1][1] = dHx[1][1] * (hx[1][1] - dbhx0 * (eR1     - ez[1][1]));

        hy[0][0] = dHy[0][0] * (hy[0][0] + dbhy0 * (ez[1][0] - ez[0][0]));
        hy[0][1] = dHy[0][1] * (hy[0][1] + dbhy0 * (ez[1][1] - ez[0][1]));
        hy[1][0] = dHy[1][0] * (hy[1][0] + dbhy0 * (eD.x     - ez[1][0]));
        hy[1][1] = dHy[1][1] * (hy[1][1] + dbhy0 * (eD.y     - ez[1][1]));

        // ---- ghost H update (same arithmetic as the neighbor's own) ----
        hyU[0] = dHyU[0] * (hyU[0] + dbhy0 * (ez[0][0] - eU.x));
        hyU[1] = dHyU[1] * (hyU[1] + dbhy0 * (ez[0][1] - eU.y));
        hxL[0] = dHxL[0] * (hxL[0] - dbhx0 * (ez[0][0] - eL0));
        hxL[1] = dHxL[1] * (hxL[1] - dbhx0 * (ez[1][0] - eL1));

        // ---- E update (all operands now in registers) ----
        float sv = p.src[n0 + s];
        float cHyv[2][2], cHxv[2][2];
        cHyv[0][0] = hy[0][0] - hyU[0];   cHxv[0][0] = hx[0][0] - hxL[0];
        cHyv[0][1] = hy[0][1] - hyU[1];   cHxv[0][1] = hx[0][1] - hx[0][0];
        cHyv[1][0] = hy[1][0] - hy[0][0]; cHxv[1][0] = hx[1][0] - hxL[1];
        cHyv[1][1] = hy[1][1] - hy[0][1]; cHxv[1][1] = hx[1][1] - hx[1][0];

#pragma unroll
        for (int a = 0; a < 2; ++a)
#pragma unroll
            for (int b = 0; b < 2; ++b) {
                float e = ez[a][b], eold = eo[a][b];
                float j = jz[a][b], jold = jo[a][b];
                float phi = ca1 * j + cb * jold + cd * e + ce * eold;
                float en = dE[a][b] *
                    (C1 * e + cbdx * cHyv[a][b] - cbdy * cHxv[a][b] - C2 * phi);
                if (isSrc[a][b]) en += sv;      // source after mask*de
                float jn = ca * j + cb * jold + cc * en + cd * e + ce * eold;
                eo[a][b] = e;  ez[a][b] = en;
                jo[a][b] = j;  jz[a][b] = jn;
            }
        // Single barrier per step: next iteration stores to the OTHER LDS
        // buffer, so late readers of this buffer can't be overwritten.
    }

    // store owned interior [Kt, Kt+Bt)^2
    if (ti >= 4 && ti < 12 && tj >= 4 && tj < 12) {
#pragma unroll
        for (int a = 0; a < 2; ++a) {
            int g = (r0 + a) * PP + c0;
            *(float2*)&nEz[g] = make_float2(ez[a][0], ez[a][1]);
            *(float2*)&nEo[g] = make_float2(eo[a][0], eo[a][1]);
            *(float2*)&nJz[g] = make_float2(jz[a][0], jz[a][1]);
            *(float2*)&nJo[g] = make_float2(jo[a][0], jo[a][1]);
            *(float2*)&nHx[g] = make_float2(hx[a][0], hx[a][1]);
            *(float2*)&nHy[g] = make_float2(hy[a][0], hy[a][1]);
        }
    }
}

// ---------------------------------------------------------------------------
// Copy padded Ez -> dense 421x421 output.
// ---------------------------------------------------------------------------
__global__ void copy_out_kernel(const float* __restrict__ ezP,
                                float* __restrict__ out)
{
    int idx = blockIdx.x * blockDim.x + threadIdx.x;
    if (idx >= NXr * NXr) return;
    int gi = idx / NXr, gj = idx - gi * NXr;
    out[idx] = ezP[(gi + PAD) * PP + (gj + PAD)];
}

// ---------------------------------------------------------------------------
extern "C" void kernel_launch(void* const* d_in, const int* in_sizes, int n_in,
                              void* d_out, int out_size, void* d_ws, size_t ws_size,
                              hipStream_t stream)
{
    const float* src    = (const float*)d_in[0];
    const float* C1     = (const float*)d_in[1];
    const float* C2     = (const float*)d_in[2];
    const float* Cb_dx  = (const float*)d_in[3];
    const float* Cb_dy  = (const float*)d_in[4];
    const float* dbhx   = (const float*)d_in[5];
    const float* dbhy   = (const float*)d_in[6];
    const float* Ca     = (const float*)d_in[7];
    const float* Cb     = (const float*)d_in[8];
    const float* Cc     = (const float*)d_in[9];
    const float* Cd     = (const float*)d_in[10];
    const float* Ce     = (const float*)d_in[11];
    const float* sig_ex = (const float*)d_in[12];
    const float* sig_ey = (const float*)d_in[13];
    const float* sig_hx = (const float*)d_in[14];
    const float* sig_hy = (const float*)d_in[15];
    // d_in[16] = n_steps (always 200) — hard-coded for graph capture.

    const double EPS0 = 1e-9 / 36.0 / M_PI;
    const double MU0  = 4.0 * M_PI * 1e-7;
    const double C0   = 1.0 / sqrt(MU0 * EPS0);
    const double DXd  = 2.5e-8, DYd = 2.5e-8;
    const double DT   = 0.99 / C0 / sqrt(1.0 / (DXd * DXd) + 1.0 / (DYd * DYd));
    const float de_fac = (float)(DT / EPS0);
    const float dh_fac = (float)(DT / MU0);

    // Workspace: [guard row PP] [12 padded fields] [6 padded tables]
    float* base = (float*)d_ws;
    float* fields = base + PP;
    float* w = fields + 12 * (size_t)FSZ;
    float* dexP = w; w += PP;
    float* deyP = w; w += PP;
    float* aexP = w; w += PP;
    float* aeyP = w; w += PP;
    float* ahxP = w; w += PP;
    float* ahyP = w; w += PP;

    PParams p;
    p.aEz = fields + 0 * (size_t)FSZ;  p.aEo = fields + 1 * (size_t)FSZ;
    p.aJz = fields + 2 * (size_t)FSZ;  p.aJo = fields + 3 * (size_t)FSZ;
    p.aHx = fields + 4 * (size_t)FSZ;  p.aHy = fields + 5 * (size_t)FSZ;
    p.bEz = fields + 6 * (size_t)FSZ;  p.bEo = fields + 7 * (size_t)FSZ;
    p.bJz = fields + 8 * (size_t)FSZ;  p.bJo = fields + 9 * (size_t)FSZ;
    p.bHx = fields + 10 * (size_t)FSZ; p.bHy = fields + 11 * (size_t)FSZ;
    p.dexP = dexP; p.deyP = deyP; p.aexP = aexP; p.aeyP = aeyP;
    p.ahxP = ahxP; p.ahyP = ahyP;
    p.C1a = C1; p.C2a = C2; p.Cbdxa = Cb_dx; p.Cbdya = Cb_dy;
    p.Caa = Ca; p.Cba = Cb; p.Cca = Cc; p.Cda = Cd; p.Cea = Ce;
    p.dbhxa = dbhx; p.dbhya = dbhy;
    p.src = src;

    init_kernel<<<512, 256, 0, stream>>>(sig_ex, sig_ey, sig_hx, sig_hy,
                                         de_fac, dh_fac,
                                         base, PP + 12 * FSZ,
                                         dexP, deyP, aexP, aeyP, ahxP, ahyP);

    dim3 grd(NBLK, NBLK), blk(256);
    for (int t = 0; t < NPHASE; ++t)
        phase_kernel<<<grd, blk, 0, stream>>>(p, t);

    // 25 phases starting from set A -> final state in set B.
    copy_out_kernel<<<(NXr * NXr + 255) / 256, 256, 0, stream>>>(p.bEz,
                                                                 (float*)d_out);
}

// Round 6
// 299.281 us; speedup vs baseline: 14.5222x; 1.2356x over previous
//
#include <hip/hip_runtime.h>
#include <math.h>

// Real grid (match reference): 421 x 421 E-grid, source at (210,210)
#define NXr 421
#define CXr 210
#define NSTEPS_C 200

// Temporal blocking: block = 16x16 threads, each thread owns a 2x2 cell quad.
// EXT=32 halo-extended tile, Kt=8 fused steps, owned interior Bt=16.
// 25 launches; kernel-launch boundaries are the device-wide barrier
// (grid.sync() forced 447 MB/dispatch of cross-XCD traffic in round 4).
// Round 6: host-side active-grid sizing -- support grows 1 cell/step from the
// point source, so phase t only launches blocks intersecting the support ball.
#define Bt   16
#define Kt   8
#define EXT  32
#define SPITCH 34                  // even => float2-aligned LDS rows
#define NBLK 27                    // 27*16 = 432 computational domain
#define NPHASE (NSTEPS_C / Kt)     // 25

// Padded zero-ring layout: fields are PP x PP with the computational domain
// [0,432)^2 at offset (PAD,PAD). Coefficient tables are zero outside the real
// 421^2 domain, so cells outside it provably stay 0 forever -> all hot
// loads/stores are unconditional float2. A zeroed guard row (PP floats) sits
// in front of the field block so ghost loads at padded row/col -1 are safe.
#define PP   448
#define PAD  8
#define CP   (CXr + PAD)           // source in padded coords: 218
#define FSZ  (PP * PP)             // floats per padded field

struct PParams {
    float *aEz, *aEo, *aJz, *aJo, *aHx, *aHy;   // state set A
    float *bEz, *bEo, *bJz, *bJo, *bHx, *bHy;   // state set B
    const float *dexP, *deyP, *aexP, *aeyP, *ahxP, *ahyP;  // padded 1-D tables
    const float *C1a, *C2a, *Cbdxa, *Cbdya;
    const float *Caa, *Cba, *Cca, *Cda, *Cea, *dbhxa, *dbhya;
    const float *src;
};

// ---------------------------------------------------------------------------
// Init: zero guard row + both padded state sets; build padded coeff tables.
// dexP/deyP fold the interior mask (nonzero only for real coords 1..419).
// Zeroing BOTH sets every call is what makes the activity skip exact: a block
// never launched leaves true zeros in both ping-pong sets.
// ---------------------------------------------------------------------------
__global__ void init_kernel(const float* __restrict__ sig_ex,
                            const float* __restrict__ sig_ey,
                            const float* __restrict__ sig_hx,
                            const float* __restrict__ sig_hy,
                            float de_fac, float dh_fac,
                            float* __restrict__ zero_base, int n_zero,
                            float* __restrict__ dexP, float* __restrict__ deyP,
                            float* __restrict__ aexP, float* __restrict__ aeyP,
                            float* __restrict__ ahxP, float* __restrict__ ahyP)
{
    int t = blockIdx.x * blockDim.x + threadIdx.x;
    int stride = gridDim.x * blockDim.x;
    for (int k = t; k < n_zero; k += stride) zero_base[k] = 0.0f;
    if (t < PP) {
        int g = t - PAD;
        dexP[t] = (g >= 1 && g <= NXr - 2) ? expf(-sig_ex[g] * de_fac) : 0.0f;
        deyP[t] = (g >= 1 && g <= NXr - 2) ? expf(-sig_ey[g] * de_fac) : 0.0f;
        aexP[t] = (g >= 0 && g <  NXr)     ? expf(-sig_ex[g] * dh_fac) : 0.0f;
        aeyP[t] = (g >= 0 && g <  NXr)     ? expf(-sig_ey[g] * dh_fac) : 0.0f;
        ahxP[t] = (g >= 0 && g <  NXr - 1) ? expf(-sig_hx[g] * dh_fac) : 0.0f;
        ahyP[t] = (g >= 0 && g <  NXr - 1) ? expf(-sig_hy[g] * dh_fac) : 0.0f;
    }
}

// ---------------------------------------------------------------------------
// One temporal-blocked phase (Kt=8 steps), ONE barrier per step.
// Ez is the only field exchanged through LDS (parity-double-buffered tile:
// step s+1 stores to the other buffer, so the single barrier is WAR-safe).
// Up/left neighbor H values are ghost registers updated redundantly from the
// exchanged Ez (identical arithmetic to the neighbor's own update).
// (bx0,by0): host-computed active-region block offset.
// ---------------------------------------------------------------------------
__global__ __launch_bounds__(256)
void phase_kernel(PParams p, int t, int bx0, int by0)
{
    __shared__ __align__(16) float sEz[2][EXT][SPITCH];

    const int tid = threadIdx.x;
    const int tj = tid & 15, ti = tid >> 4;
    const int li0 = 2 * ti, lj0 = 2 * tj;
    const int r0 = ((int)blockIdx.x + bx0) * Bt + li0;  // padded row, cell(0,*)
    const int c0 = ((int)blockIdx.y + by0) * Bt + lj0;  // padded col, cell(*,0)

    const float ca = p.Caa[0], cb = p.Cba[0], cc = p.Cca[0];
    const float cd = p.Cda[0], ce = p.Cea[0];
    const float ca1 = ca + 1.0f;
    const float C1 = p.C1a[0], C2 = p.C2a[0];
    const float cbdx = p.Cbdxa[0], cbdy = p.Cbdya[0];
    const float dbhx0 = p.dbhxa[0], dbhy0 = p.dbhya[0];

    // Per-cell damping products (interior mask folded into dE) + ghost damping
    float dHx[2][2], dHy[2][2], dE[2][2], dHyU[2], dHxL[2];
    bool isSrc[2][2];
#pragma unroll
    for (int a = 0; a < 2; ++a)
#pragma unroll
        for (int b = 0; b < 2; ++b) {
            dHx[a][b] = p.aexP[r0 + a] * p.ahyP[c0 + b];
            dHy[a][b] = p.ahxP[r0 + a] * p.aeyP[c0 + b];
            dE[a][b]  = p.dexP[r0 + a] * p.deyP[c0 + b];
            isSrc[a][b] = (r0 + a == CP) && (c0 + b == CP);
        }
    {
        float ahxU = (r0 > 0) ? p.ahxP[r0 - 1] : 0.0f;   // table idx guard
        float ahyL = (c0 > 0) ? p.ahyP[c0 - 1] : 0.0f;
        dHyU[0] = ahxU * p.aeyP[c0];
        dHyU[1] = ahxU * p.aeyP[c0 + 1];
        dHxL[0] = p.aexP[r0] * ahyL;
        dHxL[1] = p.aexP[r0 + 1] * ahyL;
    }

    const bool odd = (t & 1) != 0;
    const float* cEz = odd ? p.bEz : p.aEz;
    const float* cEo = odd ? p.bEo : p.aEo;
    const float* cJz = odd ? p.bJz : p.aJz;
    const float* cJo = odd ? p.bJo : p.aJo;
    const float* cHx = odd ? p.bHx : p.aHx;
    const float* cHy = odd ? p.bHy : p.aHy;
    float* nEz = odd ? p.aEz : p.bEz;
    float* nEo = odd ? p.aEo : p.bEo;
    float* nJz = odd ? p.aJz : p.bJz;
    float* nJo = odd ? p.aJo : p.bJo;
    float* nHx = odd ? p.aHx : p.bHx;
    float* nHy = odd ? p.aHy : p.bHy;

    // Load 2x2 register state (unconditional padded float2)
    float ez[2][2], eo[2][2], jz[2][2], jo[2][2], hx[2][2], hy[2][2];
#pragma unroll
    for (int a = 0; a < 2; ++a) {
        int g = (r0 + a) * PP + c0;
        float2 v;
        v = *(const float2*)&cEz[g]; ez[a][0] = v.x; ez[a][1] = v.y;
        v = *(const float2*)&cEo[g]; eo[a][0] = v.x; eo[a][1] = v.y;
        v = *(const float2*)&cJz[g]; jz[a][0] = v.x; jz[a][1] = v.y;
        v = *(const float2*)&cJo[g]; jo[a][0] = v.x; jo[a][1] = v.y;
        v = *(const float2*)&cHx[g]; hx[a][0] = v.x; hx[a][1] = v.y;
        v = *(const float2*)&cHy[g]; hy[a][0] = v.x; hy[a][1] = v.y;
    }
    // Ghost H (row above / col left of the quad); guard row makes idx -1 safe
    float hyU[2], hxL[2];
    {
        float2 v = *(const float2*)&cHy[(r0 - 1) * PP + c0];
        hyU[0] = v.x; hyU[1] = v.y;
        hxL[0] = cHx[r0 * PP + c0 - 1];
        hxL[1] = cHx[(r0 + 1) * PP + c0 - 1];
    }

    const bool edgeR = (tj == 15), edgeD = (ti == 15);
    const bool edgeU = (ti == 0),  edgeL = (tj == 0);
    const int n0 = t * Kt;

    for (int s = 0; s < Kt; ++s) {
        float (*S)[SPITCH] = sEz[s & 1];
        // publish all 4 Ez cells
        *(float2*)&S[li0][lj0]     = make_float2(ez[0][0], ez[0][1]);
        *(float2*)&S[li0 + 1][lj0] = make_float2(ez[1][0], ez[1][1]);
        __syncthreads();

        float eR0 = edgeR ? 0.0f : S[li0][lj0 + 2];
        float eR1 = edgeR ? 0.0f : S[li0 + 1][lj0 + 2];
        float2 eD  = edgeD ? make_float2(0.0f, 0.0f)
                           : *(float2*)&S[li0 + 2][lj0];
        float2 eU  = edgeU ? make_float2(0.0f, 0.0f)
                           : *(float2*)&S[li0 - 1][lj0];
        float eL0 = edgeL ? 0.0f : S[li0][lj0 - 1];
        float eL1 = edgeL ? 0.0f : S[li0 + 1][lj0 - 1];

        // ---- H update (own 2x2) ----
        hx[0][0] = dHx[0][0] * (hx[0][0] - dbhx0 * (ez[0][1] - ez[0][0]));
        hx[0][1] = dHx[0][1] * (hx[0][1] - dbhx0 * (eR0     - ez[0][1]));
        hx[1][0] = dHx[1][0] * (hx[1][0] - dbhx0 * (ez[1][1] - ez[1][0]));
        hx[1][1] = dHx[1][1] * (hx[1][1] - dbhx0 * (eR1     - ez[1][1]));

        hy[0][0] = dHy[0][0] * (hy[0][0] + dbhy0 * (ez[1][0] - ez[0][0]));
        hy[0][1] = dHy[0][1] * (hy[0][1] + dbhy0 * (ez[1][1] - ez[0][1]));
        hy[1][0] = dHy[1][0] * (hy[1][0] + dbhy0 * (eD.x     - ez[1][0]));
        hy[1][1] = dHy[1][1] * (hy[1][1] + dbhy0 * (eD.y     - ez[1][1]));

        // ---- ghost H update (same arithmetic as the neighbor's own) ----
        hyU[0] = dHyU[0] * (hyU[0] + dbhy0 * (ez[0][0] - eU.x));
        hyU[1] = dHyU[1] * (hyU[1] + dbhy0 * (ez[0][1] - eU.y));
        hxL[0] = dHxL[0] * (hxL[0] - dbhx0 * (ez[0][0] - eL0));
        hxL[1] = dHxL[1] * (hxL[1] - dbhx0 * (ez[1][0] - eL1));

        // ---- E update (all operands in registers) ----
        float sv = p.src[n0 + s];
        float cHyv[2][2], cHxv[2][2];
        cHyv[0][0] = hy[0][0] - hyU[0];   cHxv[0][0] = hx[0][0] - hxL[0];
        cHyv[0][1] = hy[0][1] - hyU[1];   cHxv[0][1] = hx[0][1] - hx[0][0];
        cHyv[1][0] = hy[1][0] - hy[0][0]; cHxv[1][0] = hx[1][0] - hxL[1];
        cHyv[1][1] = hy[1][1] - hy[0][1]; cHxv[1][1] = hx[1][1] - hx[1][0];

#pragma unroll
        for (int a = 0; a < 2; ++a)
#pragma unroll
            for (int b = 0; b < 2; ++b) {
                float e = ez[a][b], eold = eo[a][b];
                float j = jz[a][b], jold = jo[a][b];
                float phi = ca1 * j + cb * jold + cd * e + ce * eold;
                float en = dE[a][b] *
                    (C1 * e + cbdx * cHyv[a][b] - cbdy * cHxv[a][b] - C2 * phi);
                if (isSrc[a][b]) en += sv;      // source after mask*de
                // jn = ca*j + cb*jo + cc*en + cd*e + ce*eo == phi - j + cc*en
                float jn = phi - j + cc * en;
                eo[a][b] = e;  ez[a][b] = en;
                jo[a][b] = j;  jz[a][b] = jn;
            }
        // Single barrier per step: next iteration stores to the OTHER LDS
        // buffer, so late readers of this buffer can't be overwritten.
    }

    // store owned interior [Kt, Kt+Bt)^2
    if (ti >= 4 && ti < 12 && tj >= 4 && tj < 12) {
#pragma unroll
        for (int a = 0; a < 2; ++a) {
            int g = (r0 + a) * PP + c0;
            *(float2*)&nEz[g] = make_float2(ez[a][0], ez[a][1]);
            *(float2*)&nEo[g] = make_float2(eo[a][0], eo[a][1]);
            *(float2*)&nJz[g] = make_float2(jz[a][0], jz[a][1]);
            *(float2*)&nJo[g] = make_float2(jo[a][0], jo[a][1]);
            *(float2*)&nHx[g] = make_float2(hx[a][0], hx[a][1]);
            *(float2*)&nHy[g] = make_float2(hy[a][0], hy[a][1]);
        }
    }
}

// ---------------------------------------------------------------------------
// Copy padded Ez -> dense 421x421 output.
// ---------------------------------------------------------------------------
__global__ void copy_out_kernel(const float* __restrict__ ezP,
                                float* __restrict__ out)
{
    int idx = blockIdx.x * blockDim.x + threadIdx.x;
    if (idx >= NXr * NXr) return;
    int gi = idx / NXr, gj = idx - gi * NXr;
    out[idx] = ezP[(gi + PAD) * PP + (gj + PAD)];
}

// ---------------------------------------------------------------------------
extern "C" void kernel_launch(void* const* d_in, const int* in_sizes, int n_in,
                              void* d_out, int out_size, void* d_ws, size_t ws_size,
                              hipStream_t stream)
{
    const float* src    = (const float*)d_in[0];
    const float* C1     = (const float*)d_in[1];
    const float* C2     = (const float*)d_in[2];
    const float* Cb_dx  = (const float*)d_in[3];
    const float* Cb_dy  = (const float*)d_in[4];
    const float* dbhx   = (const float*)d_in[5];
    const float* dbhy   = (const float*)d_in[6];
    const float* Ca     = (const float*)d_in[7];
    const float* Cb     = (const float*)d_in[8];
    const float* Cc     = (const float*)d_in[9];
    const float* Cd     = (const float*)d_in[10];
    const float* Ce     = (const float*)d_in[11];
    const float* sig_ex = (const float*)d_in[12];
    const float* sig_ey = (const float*)d_in[13];
    const float* sig_hx = (const float*)d_in[14];
    const float* sig_hy = (const float*)d_in[15];
    // d_in[16] = n_steps (always 200) — hard-coded for graph capture.

    const double EPS0 = 1e-9 / 36.0 / M_PI;
    const double MU0  = 4.0 * M_PI * 1e-7;
    const double C0   = 1.0 / sqrt(MU0 * EPS0);
    const double DXd  = 2.5e-8, DYd = 2.5e-8;
    const double DT   = 0.99 / C0 / sqrt(1.0 / (DXd * DXd) + 1.0 / (DYd * DYd));
    const float de_fac = (float)(DT / EPS0);
    const float dh_fac = (float)(DT / MU0);

    // Workspace: [guard row PP] [12 padded fields] [6 padded tables]
    float* base = (float*)d_ws;
    float* fields = base + PP;
    float* w = fields + 12 * (size_t)FSZ;
    float* dexP = w; w += PP;
    float* deyP = w; w += PP;
    float* aexP = w; w += PP;
    float* aeyP = w; w += PP;
    float* ahxP = w; w += PP;
    float* ahyP = w; w += PP;

    PParams p;
    p.aEz = fields + 0 * (size_t)FSZ;  p.aEo = fields + 1 * (size_t)FSZ;
    p.aJz = fields + 2 * (size_t)FSZ;  p.aJo = fields + 3 * (size_t)FSZ;
    p.aHx = fields + 4 * (size_t)FSZ;  p.aHy = fields + 5 * (size_t)FSZ;
    p.bEz = fields + 6 * (size_t)FSZ;  p.bEo = fields + 7 * (size_t)FSZ;
    p.bJz = fields + 8 * (size_t)FSZ;  p.bJo = fields + 9 * (size_t)FSZ;
    p.bHx = fields + 10 * (size_t)FSZ; p.bHy = fields + 11 * (size_t)FSZ;
    p.dexP = dexP; p.deyP = deyP; p.aexP = aexP; p.aeyP = aeyP;
    p.ahxP = ahxP; p.ahyP = ahyP;
    p.C1a = C1; p.C2a = C2; p.Cbdxa = Cb_dx; p.Cbdya = Cb_dy;
    p.Caa = Ca; p.Cba = Cb; p.Cca = Cc; p.Cda = Cd; p.Cea = Ce;
    p.dbhxa = dbhx; p.dbhya = dbhy;
    p.src = src;

    init_kernel<<<512, 256, 0, stream>>>(sig_ex, sig_ey, sig_hx, sig_hy,
                                         de_fac, dh_fac,
                                         base, PP + 12 * FSZ,
                                         dexP, deyP, aexP, aeyP, ahxP, ahyP);

    dim3 blk(256);
    for (int t = 0; t < NPHASE; ++t) {
        // Support bound: after n steps, fields are confined to a Chebyshev
        // ball of radius n-1 around the source (1 cell/step growth). End of
        // phase t is step 8(t+1) -> radius 8t+7; +5 slack -> r = 8t+12.
        // Launch only blocks whose 32^2 tile intersects [CP-r, CP+r]^2.
        // t-only formula -> identical grid every call (graph-capture safe).
        int r  = 8 * t + 12;
        int lo = CP - r, hi = CP + r;
        int b0 = (lo - (EXT - 1)) / 16; if (b0 < 0) b0 = 0;
        int b1 = hi / 16;               if (b1 > NBLK - 1) b1 = NBLK - 1;
        dim3 g(b1 - b0 + 1, b1 - b0 + 1);
        phase_kernel<<<g, blk, 0, stream>>>(p, t, b0, b0);
    }

    // 25 phases starting from set A -> final state in set B.
    copy_out_kernel<<<(NXr * NXr + 255) / 256, 256, 0, stream>>>(p.bEz,
                                                                 (float*)d_out);
}